// Round 1
// baseline (681.788 us; speedup 1.0000x reference)
//
#include <hip/hip_runtime.h>

#define BB 2
#define TT 2048
#define DD 1024
#define NN 16
#define LL 16
#define CC (TT / LL)      /* 128 chunks */
#define SS 32             /* segments */
#define CPS (CC / SS)     /* 4 chunks per segment */

// ---------------------------------------------------------------------------
// K1a: per-(b,seg,d,n-pair) segment affine transform. h_out = h*P + Q.
// Lane owns n = {2*ng, 2*ng+1}; bmat read as float2 (wave: 512B contiguous).
// ---------------------------------------------------------------------------
__global__ __launch_bounds__(256, 4) void k1a_segxform(
    const float* __restrict__ delta,
    const float* __restrict__ u,
    const float* __restrict__ bmat,
    const float* __restrict__ A_log,
    float* __restrict__ Pseg,
    float* __restrict__ Qseg)
{
    int g   = blockIdx.x * 256 + threadIdx.x;   // BB*SS*DD*8 threads
    int ng  = g & 7;
    int d   = (g >> 3) & (DD - 1);
    int seg = (g >> 13) & (SS - 1);
    int b   = g >> 18;
    int n0  = ng * 2;

    float A0 = -__expf(A_log[n0]);
    float A1 = -__expf(A_log[n0 + 1]);
    float r0 = 1.0f / (A0 + 1e-12f);
    float r1 = 1.0f / (A1 + 1e-12f);

    float P0 = 1.0f, P1 = 1.0f, Q0 = 0.0f, Q1 = 0.0f;
    int t0seg = seg * (TT / SS);
    for (int c = 0; c < CPS; ++c) {
        int t0   = t0seg + c * LL;
        int base = (b * TT + t0) * DD + d;

        float dl[LL];
        #pragma unroll
        for (int t = 0; t < LL; ++t) dl[t] = delta[base + t * DD];
        float  uu0 = u[base];
        float2 bv  = *reinterpret_cast<const float2*>(&bmat[(long)base * NN + n0]);

        float p0 = 1.0f, p1 = 1.0f, q0 = 0.0f, q1 = 0.0f;
        #pragma unroll
        for (int t = 0; t < LL; ++t) {
            float dA0 = fminf(fmaxf(dl[t] * A0, -10.0f), 10.0f);
            float dA1 = fminf(fmaxf(dl[t] * A1, -10.0f), 10.0f);
            float e0 = __expf(dA0), e1 = __expf(dA1);
            if (t == 0) {
                float f0 = (fabsf(dA0) < 1e-4f) ? dl[t] : (e0 - 1.0f) * r0;
                float f1 = (fabsf(dA1) < 1e-4f) ? dl[t] : (e1 - 1.0f) * r1;
                q0 = f0 * (bv.x * uu0) * e0;    // Bu[0]*fw[0], fw[0]=eA[0]
                q1 = f1 * (bv.y * uu0) * e1;
            }
            p0 *= e0; p1 *= e1;
        }
        P0 *= p0; Q0 = Q0 * p0 + q0;            // compose: h -> h*p + q
        P1 *= p1; Q1 = Q1 * p1 + q1;
    }
    int oidx = ((b * SS + seg) * DD + d) * NN + n0;
    *reinterpret_cast<float2*>(&Pseg[oidx]) = make_float2(P0, P1);
    *reinterpret_cast<float2*>(&Qseg[oidx]) = make_float2(Q0, Q1);
}

// ---------------------------------------------------------------------------
// K1b: tiny sequential scan over S segments per (b,d,n). Writes h_in table.
// ---------------------------------------------------------------------------
__global__ __launch_bounds__(256) void k1b_scan(
    const float* __restrict__ Pseg,
    const float* __restrict__ Qseg,
    float* __restrict__ hin,
    int S)
{
    int g  = blockIdx.x * 256 + threadIdx.x;    // B*D*N threads
    int dn = g & (DD * NN - 1);
    int b  = g >> 14;

    float h = 0.0f;
    for (int s = 0; s < S; ++s) {
        int idx = (b * S + s) * (DD * NN) + dn; // coalesced across lanes
        hin[idx] = h;
        h = h * Pseg[idx] + Qseg[idx];
    }
}

// ---------------------------------------------------------------------------
// K2: lane owns (b,seg,d, n-pair {2ng,2ng+1}); 8 lanes per d.
// Pass A (forward over chunk): cp[t]=prefix prod of eA, g[t]=Bu[t]*fw[t]
//   (float2 bmat loads; per-t state = 64 regs under __launch_bounds__(256,4)).
// Pass B (reverse t): running suffix-sum cs -> y[t] = sum_n c*(h*cp[t]+cs);
//   cmat loaded only here (each row once), butterfly over the 8 n-lanes.
// ---------------------------------------------------------------------------
__global__ __launch_bounds__(256, 4) void k2_main(
    const float* __restrict__ delta,
    const float* __restrict__ u,
    const float* __restrict__ bmat,
    const float* __restrict__ cmat,
    const float* __restrict__ A_log,
    const float* __restrict__ hin,
    float* __restrict__ out)
{
    int g   = blockIdx.x * 256 + threadIdx.x;   // BB*SS*DD*8 threads
    int ng  = g & 7;
    int d   = (g >> 3) & (DD - 1);
    int seg = (g >> 13) & (SS - 1);
    int b   = g >> 18;
    int n0  = ng * 2;

    float A0 = -__expf(A_log[n0]);
    float A1 = -__expf(A_log[n0 + 1]);
    float r0 = 1.0f / (A0 + 1e-12f);
    float r1 = 1.0f / (A1 + 1e-12f);

    float2 hv = *reinterpret_cast<const float2*>(
        &hin[((b * SS + seg) * DD + d) * NN + n0]);
    float h0 = hv.x, h1 = hv.y;

    int t0seg = seg * (TT / SS);
    for (int c = 0; c < CPS; ++c) {
        int  t0    = t0seg + c * LL;
        int  base  = (b * TT + t0) * DD + d;
        long nbase = (long)base * NN + n0;

        float cp0[LL], cp1[LL], g0[LL], g1[LL];
        float pr0 = 1.0f, pr1 = 1.0f;
        #pragma unroll
        for (int t = 0; t < LL; ++t) {
            float  dlv = delta[base + t * DD];
            float  uv  = u[base + t * DD];
            float2 bv  = *reinterpret_cast<const float2*>(
                &bmat[nbase + (long)t * (DD * NN)]);
            float dA0 = fminf(fmaxf(dlv * A0, -10.0f), 10.0f);
            float dA1 = fminf(fmaxf(dlv * A1, -10.0f), 10.0f);
            float e0 = __expf(dA0), e1 = __expf(dA1);
            float f0 = (fabsf(dA0) < 1e-4f) ? dlv : (e0 - 1.0f) * r0;
            float f1 = (fabsf(dA1) < 1e-4f) ? dlv : (e1 - 1.0f) * r1;
            float Bu0 = f0 * (bv.x * uv);
            float Bu1 = f1 * (bv.y * uv);
            pr0 *= e0; pr1 *= e1;
            cp0[t] = pr0; cp1[t] = pr1;
            g0[t] = Bu0 * ((t < LL - 1) ? e0 : 1.0f);   // fw[t]
            g1[t] = Bu1 * ((t < LL - 1) ? e1 : 1.0f);
        }

        float cs0 = 0.0f, cs1 = 0.0f;
        #pragma unroll
        for (int k = 0; k < LL; ++k) {
            int t = LL - 1 - k;                 // y[t] needs cs[LL-1-t] = cs[k]
            cs0 += g0[k];
            cs1 += g1[k];
            float2 cv = *reinterpret_cast<const float2*>(
                &cmat[nbase + (long)t * (DD * NN)]);
            float v = cv.x * (h0 * cp0[t] + cs0)
                    + cv.y * (h1 * cp1[t] + cs1);
            v += __shfl_xor(v, 1);
            v += __shfl_xor(v, 2);
            v += __shfl_xor(v, 4);              // full sum over 16 n (8 lanes x 2)
            if (ng == 0) out[base + t * DD] = v;
        }

        h0 = h0 * cp0[LL - 1] + g0[0];          // carry: h*prod(eA) + Bu[0]*eA[0]
        h1 = h1 * cp1[LL - 1] + g1[0];
    }
}

// ---------------------------------------------------------------------------
extern "C" void kernel_launch(void* const* d_in, const int* in_sizes, int n_in,
                              void* d_out, int out_size, void* d_ws, size_t ws_size,
                              hipStream_t stream) {
    (void)in_sizes; (void)n_in; (void)out_size; (void)ws_size;

    const float* u     = (const float*)d_in[0];
    const float* delta = (const float*)d_in[1];
    const float* bmat  = (const float*)d_in[2];
    const float* cmat  = (const float*)d_in[3];
    const float* A_log = (const float*)d_in[4];
    float* out = (float*)d_out;

    size_t tbl = (size_t)BB * SS * DD * NN;     // 1M floats = 4 MB each
    float* Pseg = (float*)d_ws;
    float* Qseg = Pseg + tbl;
    float* hin  = Qseg + tbl;                   // 12 MB total workspace

    k1a_segxform<<<(BB * SS * DD * (NN / 2)) / 256, 256, 0, stream>>>(
        delta, u, bmat, A_log, Pseg, Qseg);
    k1b_scan<<<(BB * DD * NN) / 256, 256, 0, stream>>>(Pseg, Qseg, hin, SS);
    k2_main<<<(BB * SS * DD * (NN / 2)) / 256, 256, 0, stream>>>(
        delta, u, bmat, cmat, A_log, hin, out);
}

// Round 2
// 580.943 us; speedup vs baseline: 1.1736x; 1.1736x over previous
//
#include <hip/hip_runtime.h>

#define BB 2
#define TT 2048
#define DD 1024
#define NN 16
#define LL 16
#define CC (TT / LL)      /* 128 chunks */
#define SS 32             /* segments */
#define CPS (CC / SS)     /* 4 chunks per segment */
#define HH 8              /* half chunk */

// ---------------------------------------------------------------------------
// K1a: per-(b,seg,d,n-pair) segment affine transform. h_out = h*P + Q.
// Lane owns n = {2*ng, 2*ng+1}; bmat read as float2 (wave: 512B contiguous).
// ---------------------------------------------------------------------------
__global__ __launch_bounds__(256, 4) void k1a_segxform(
    const float* __restrict__ delta,
    const float* __restrict__ u,
    const float* __restrict__ bmat,
    const float* __restrict__ A_log,
    float* __restrict__ Pseg,
    float* __restrict__ Qseg)
{
    int g   = blockIdx.x * 256 + threadIdx.x;   // BB*SS*DD*8 threads
    int ng  = g & 7;
    int d   = (g >> 3) & (DD - 1);
    int seg = (g >> 13) & (SS - 1);
    int b   = g >> 18;
    int n0  = ng * 2;

    float A0 = -__expf(A_log[n0]);
    float A1 = -__expf(A_log[n0 + 1]);
    float r0 = 1.0f / (A0 + 1e-12f);
    float r1 = 1.0f / (A1 + 1e-12f);

    float P0 = 1.0f, P1 = 1.0f, Q0 = 0.0f, Q1 = 0.0f;
    int t0seg = seg * (TT / SS);
    for (int c = 0; c < CPS; ++c) {
        int t0   = t0seg + c * LL;
        int base = (b * TT + t0) * DD + d;

        float dl[LL];
        #pragma unroll
        for (int t = 0; t < LL; ++t) dl[t] = delta[base + t * DD];
        float  uu0 = u[base];
        float2 bv  = *reinterpret_cast<const float2*>(&bmat[(long)base * NN + n0]);

        float p0 = 1.0f, p1 = 1.0f, q0 = 0.0f, q1 = 0.0f;
        #pragma unroll
        for (int t = 0; t < LL; ++t) {
            float dA0 = fminf(fmaxf(dl[t] * A0, -10.0f), 10.0f);
            float dA1 = fminf(fmaxf(dl[t] * A1, -10.0f), 10.0f);
            float e0 = __expf(dA0), e1 = __expf(dA1);
            if (t == 0) {
                float f0 = (fabsf(dA0) < 1e-4f) ? dl[t] : (e0 - 1.0f) * r0;
                float f1 = (fabsf(dA1) < 1e-4f) ? dl[t] : (e1 - 1.0f) * r1;
                q0 = f0 * (bv.x * uu0) * e0;    // Bu[0]*fw[0], fw[0]=eA[0]
                q1 = f1 * (bv.y * uu0) * e1;
            }
            p0 *= e0; p1 *= e1;
        }
        P0 *= p0; Q0 = Q0 * p0 + q0;            // compose: h -> h*p + q
        P1 *= p1; Q1 = Q1 * p1 + q1;
    }
    int oidx = ((b * SS + seg) * DD + d) * NN + n0;
    *reinterpret_cast<float2*>(&Pseg[oidx]) = make_float2(P0, P1);
    *reinterpret_cast<float2*>(&Qseg[oidx]) = make_float2(Q0, Q1);
}

// ---------------------------------------------------------------------------
// K1b: tiny sequential scan over S segments per (b,d,n). Writes h_in table.
// ---------------------------------------------------------------------------
__global__ __launch_bounds__(256) void k1b_scan(
    const float* __restrict__ Pseg,
    const float* __restrict__ Qseg,
    float* __restrict__ hin,
    int S)
{
    int g  = blockIdx.x * 256 + threadIdx.x;    // B*D*N threads
    int dn = g & (DD * NN - 1);
    int b  = g >> 14;

    float h = 0.0f;
    for (int s = 0; s < S; ++s) {
        int idx = (b * S + s) * (DD * NN) + dn; // coalesced across lanes
        hin[idx] = h;
        h = h * Pseg[idx] + Qseg[idx];
    }
}

// ---------------------------------------------------------------------------
// K2: lane owns (b,seg,d, n-pair {2ng,2ng+1}); 8 lanes per d.
// Half-chunk schedule to keep per-thread state at 32 array floats (no spill):
//   Phase 1 (t=0..7): store cp[t] (prefix prod) and pf[t] (prefix sum of
//     g[t]=Bu[t]*fw[t]).
//   Phase 2 (j=0..7, row r=8+j ascending): cp[r] = running product (no
//     storage); cs = pf[7] + g[8..r] running suffix. Emits TWO outputs/step:
//       y[r]   = sum_n c[r]  *(h*cp[r]    + pf[7-j])   (15-r = 7-j)
//       y[7-j] = sum_n c[7-j]*(h*cp[7-j]  + cs)        (15-(7-j) = r)
//   All array indices compile-time constant under unroll. Accumulation order
//   (cumprod fwd, cumsum fwd) identical to reference.
// Carry: h <- h*cp[15] + pf[0]  (reference: Bu_term[L-1] = g[0]).
// ---------------------------------------------------------------------------
__global__ __launch_bounds__(256, 2) void k2_main(
    const float* __restrict__ delta,
    const float* __restrict__ u,
    const float* __restrict__ bmat,
    const float* __restrict__ cmat,
    const float* __restrict__ A_log,
    const float* __restrict__ hin,
    float* __restrict__ out)
{
    int g   = blockIdx.x * 256 + threadIdx.x;   // BB*SS*DD*8 threads
    int ng  = g & 7;
    int d   = (g >> 3) & (DD - 1);
    int seg = (g >> 13) & (SS - 1);
    int b   = g >> 18;
    int n0  = ng * 2;

    float A0 = -__expf(A_log[n0]);
    float A1 = -__expf(A_log[n0 + 1]);
    float r0 = 1.0f / (A0 + 1e-12f);
    float r1 = 1.0f / (A1 + 1e-12f);

    float2 hv = *reinterpret_cast<const float2*>(
        &hin[((b * SS + seg) * DD + d) * NN + n0]);
    float h0 = hv.x, h1 = hv.y;

    int t0seg = seg * (TT / SS);
    for (int c = 0; c < CPS; ++c) {
        int  base  = (b * TT + t0seg + c * LL) * DD + d;
        long nbase = (long)base * NN + n0;

        // ---- phase 1: rows 0..7 ----
        float cpA[HH], cpB[HH], pfA[HH], pfB[HH];
        float pr0 = 1.0f, pr1 = 1.0f, s0 = 0.0f, s1 = 0.0f;
        #pragma unroll
        for (int j = 0; j < HH; ++j) {
            float  dlv = delta[base + j * DD];
            float  uv  = u[base + j * DD];
            float2 bv  = *reinterpret_cast<const float2*>(
                &bmat[nbase + (long)j * (DD * NN)]);
            float dA0 = fminf(fmaxf(dlv * A0, -10.0f), 10.0f);
            float dA1 = fminf(fmaxf(dlv * A1, -10.0f), 10.0f);
            float e0 = __expf(dA0), e1 = __expf(dA1);
            float f0 = (fabsf(dA0) < 1e-4f) ? dlv : (e0 - 1.0f) * r0;
            float f1 = (fabsf(dA1) < 1e-4f) ? dlv : (e1 - 1.0f) * r1;
            pr0 *= e0; pr1 *= e1;
            cpA[j] = pr0; cpB[j] = pr1;
            s0 += f0 * (bv.x * uv) * e0;        // fw[j] = eA[j] for j < 15
            s1 += f1 * (bv.y * uv) * e1;
            pfA[j] = s0; pfB[j] = s1;
        }

        // ---- phase 2: rows 8..15 ascending; two outputs per step ----
        float cs0 = s0, cs1 = s1;               // cs = pf[7]
        #pragma unroll
        for (int j = 0; j < HH; ++j) {
            int rr = HH + j;                    // 8..15
            int tl = HH - 1 - j;                // 7..0
            float  dlv = delta[base + rr * DD];
            float  uv  = u[base + rr * DD];
            float2 bv  = *reinterpret_cast<const float2*>(
                &bmat[nbase + (long)rr * (DD * NN)]);
            float2 cvh = *reinterpret_cast<const float2*>(
                &cmat[nbase + (long)rr * (DD * NN)]);
            float2 cvl = *reinterpret_cast<const float2*>(
                &cmat[nbase + (long)tl * (DD * NN)]);
            float dA0 = fminf(fmaxf(dlv * A0, -10.0f), 10.0f);
            float dA1 = fminf(fmaxf(dlv * A1, -10.0f), 10.0f);
            float e0 = __expf(dA0), e1 = __expf(dA1);
            float f0 = (fabsf(dA0) < 1e-4f) ? dlv : (e0 - 1.0f) * r0;
            float f1 = (fabsf(dA1) < 1e-4f) ? dlv : (e1 - 1.0f) * r1;
            pr0 *= e0; pr1 *= e1;               // cp[rr], fwd cumprod order
            float fw0 = (rr < LL - 1) ? e0 : 1.0f;
            float fw1 = (rr < LL - 1) ? e1 : 1.0f;
            cs0 += f0 * (bv.x * uv) * fw0;      // cs = pf[rr], fwd cumsum order
            cs1 += f1 * (bv.y * uv) * fw1;

            float vhi = cvh.x * (h0 * pr0 + pfA[tl])
                      + cvh.y * (h1 * pr1 + pfB[tl]);
            float vlo = cvl.x * (h0 * cpA[tl] + cs0)
                      + cvl.y * (h1 * cpB[tl] + cs1);
            vhi += __shfl_xor(vhi, 1);
            vhi += __shfl_xor(vhi, 2);
            vhi += __shfl_xor(vhi, 4);          // sum over 8 ng-lanes (16 n)
            vlo += __shfl_xor(vlo, 1);
            vlo += __shfl_xor(vlo, 2);
            vlo += __shfl_xor(vlo, 4);
            if (ng == 0) {
                out[base + rr * DD] = vhi;
                out[base + tl * DD] = vlo;
            }
        }

        h0 = h0 * pr0 + pfA[0];                 // h*cp[15] + g[0]
        h1 = h1 * pr1 + pfB[0];
    }
}

// ---------------------------------------------------------------------------
extern "C" void kernel_launch(void* const* d_in, const int* in_sizes, int n_in,
                              void* d_out, int out_size, void* d_ws, size_t ws_size,
                              hipStream_t stream) {
    (void)in_sizes; (void)n_in; (void)out_size; (void)ws_size;

    const float* u     = (const float*)d_in[0];
    const float* delta = (const float*)d_in[1];
    const float* bmat  = (const float*)d_in[2];
    const float* cmat  = (const float*)d_in[3];
    const float* A_log = (const float*)d_in[4];
    float* out = (float*)d_out;

    size_t tbl = (size_t)BB * SS * DD * NN;     // 1M floats = 4 MB each
    float* Pseg = (float*)d_ws;
    float* Qseg = Pseg + tbl;
    float* hin  = Qseg + tbl;                   // 12 MB total workspace

    k1a_segxform<<<(BB * SS * DD * (NN / 2)) / 256, 256, 0, stream>>>(
        delta, u, bmat, A_log, Pseg, Qseg);
    k1b_scan<<<(BB * DD * NN) / 256, 256, 0, stream>>>(Pseg, Qseg, hin, SS);
    k2_main<<<(BB * SS * DD * (NN / 2)) / 256, 256, 0, stream>>>(
        delta, u, bmat, cmat, A_log, hin, out);
}

// Round 3
// 566.642 us; speedup vs baseline: 1.2032x; 1.0252x over previous
//
#include <hip/hip_runtime.h>

#define BB 2
#define TT 2048
#define DD 1024
#define NN 16
#define LL 16
#define CC (TT / LL)      /* 128 chunks */
#define SS 32             /* segments */
#define CPS (CC / SS)     /* 4 chunks per segment */

typedef float f32x2 __attribute__((ext_vector_type(2)));

// Forced-VGPR batched loads: saddr form, u32 per-lane voffset.
#define GLD1(dst, voff, sbase) \
    asm volatile("global_load_dword %0, %1, %2" \
                 : "=v"(dst) : "v"(voff), "s"(sbase))
#define GLD2(dst, voff, sbase) \
    asm volatile("global_load_dwordx2 %0, %1, %2" \
                 : "=v"(dst) : "v"(voff), "s"(sbase))

// ---------------------------------------------------------------------------
// K1a: per-(b,seg,d,n-pair) segment affine transform. h_out = h*P + Q.
// (unchanged from round 2 — small kernel, isolating the k2 change)
// ---------------------------------------------------------------------------
__global__ __launch_bounds__(256, 4) void k1a_segxform(
    const float* __restrict__ delta,
    const float* __restrict__ u,
    const float* __restrict__ bmat,
    const float* __restrict__ A_log,
    float* __restrict__ Pseg,
    float* __restrict__ Qseg)
{
    int g   = blockIdx.x * 256 + threadIdx.x;   // BB*SS*DD*8 threads
    int ng  = g & 7;
    int d   = (g >> 3) & (DD - 1);
    int seg = (g >> 13) & (SS - 1);
    int b   = g >> 18;
    int n0  = ng * 2;

    float A0 = -__expf(A_log[n0]);
    float A1 = -__expf(A_log[n0 + 1]);
    float r0 = 1.0f / (A0 + 1e-12f);
    float r1 = 1.0f / (A1 + 1e-12f);

    float P0 = 1.0f, P1 = 1.0f, Q0 = 0.0f, Q1 = 0.0f;
    int t0seg = seg * (TT / SS);
    for (int c = 0; c < CPS; ++c) {
        int t0   = t0seg + c * LL;
        int base = (b * TT + t0) * DD + d;

        float dl[LL];
        #pragma unroll
        for (int t = 0; t < LL; ++t) dl[t] = delta[base + t * DD];
        float  uu0 = u[base];
        float2 bv  = *reinterpret_cast<const float2*>(&bmat[(long)base * NN + n0]);

        float p0 = 1.0f, p1 = 1.0f, q0 = 0.0f, q1 = 0.0f;
        #pragma unroll
        for (int t = 0; t < LL; ++t) {
            float dA0 = fminf(fmaxf(dl[t] * A0, -10.0f), 10.0f);
            float dA1 = fminf(fmaxf(dl[t] * A1, -10.0f), 10.0f);
            float e0 = __expf(dA0), e1 = __expf(dA1);
            if (t == 0) {
                float f0 = (fabsf(dA0) < 1e-4f) ? dl[t] : (e0 - 1.0f) * r0;
                float f1 = (fabsf(dA1) < 1e-4f) ? dl[t] : (e1 - 1.0f) * r1;
                q0 = f0 * (bv.x * uu0) * e0;    // Bu[0]*fw[0], fw[0]=eA[0]
                q1 = f1 * (bv.y * uu0) * e1;
            }
            p0 *= e0; p1 *= e1;
        }
        P0 *= p0; Q0 = Q0 * p0 + q0;            // compose: h -> h*p + q
        P1 *= p1; Q1 = Q1 * p1 + q1;
    }
    int oidx = ((b * SS + seg) * DD + d) * NN + n0;
    *reinterpret_cast<float2*>(&Pseg[oidx]) = make_float2(P0, P1);
    *reinterpret_cast<float2*>(&Qseg[oidx]) = make_float2(Q0, Q1);
}

// ---------------------------------------------------------------------------
// K1b: tiny sequential scan over S segments per (b,d,n). Writes h_in table.
// ---------------------------------------------------------------------------
__global__ __launch_bounds__(256) void k1b_scan(
    const float* __restrict__ Pseg,
    const float* __restrict__ Qseg,
    float* __restrict__ hin,
    int S)
{
    int g  = blockIdx.x * 256 + threadIdx.x;    // B*D*N threads
    int dn = g & (DD * NN - 1);
    int b  = g >> 14;

    float h = 0.0f;
    for (int s = 0; s < S; ++s) {
        int idx = (b * S + s) * (DD * NN) + dn; // coalesced across lanes
        hin[idx] = h;
        h = h * Pseg[idx] + Qseg[idx];
    }
}

// ---------------------------------------------------------------------------
// K2: lane owns (b,seg,d, n-pair {2ng,2ng+1}); 8 lanes per d.
// Per chunk: issue ALL 64 loads (16 delta + 16 u + 16 bmat.f2 + 16 cmat.f2)
// via inline-asm (forces VGPR destinations -> ~17 KB in flight per wave),
// then ONE s_waitcnt vmcnt(0) + sched_barrier(0), then pure-VALU compute:
//   fwd t=0..15: cp[t] = cumprod(eA), pf[t] = cumsum(g), g = Bu*fw
//   out t=0..15: y[t] = sum_n c[t]*(h*cp[t] + pf[15-t]); butterfly over 8 ng.
// Carry: h <- h*cp[15] + pf[0]. Accumulation order identical to reference.
// ---------------------------------------------------------------------------
__global__ __launch_bounds__(256, 1) void k2_main(
    const float* __restrict__ delta,
    const float* __restrict__ u,
    const float* __restrict__ bmat,
    const float* __restrict__ cmat,
    const float* __restrict__ A_log,
    const float* __restrict__ hin,
    float* __restrict__ out)
{
    int g   = blockIdx.x * 256 + threadIdx.x;   // BB*SS*DD*8 threads
    int ng  = g & 7;
    int d   = (g >> 3) & (DD - 1);
    int seg = (g >> 13) & (SS - 1);
    int b   = g >> 18;
    int n0  = ng * 2;

    float A0 = -__expf(A_log[n0]);
    float A1 = -__expf(A_log[n0 + 1]);
    float r0 = 1.0f / (A0 + 1e-12f);
    float r1 = 1.0f / (A1 + 1e-12f);

    float2 hv = *reinterpret_cast<const float2*>(
        &hin[((b * SS + seg) * DD + d) * NN + n0]);
    float h0 = hv.x, h1 = hv.y;

    int t0seg = seg * (TT / SS);
    for (int c = 0; c < CPS; ++c) {
        int base = (b * TT + t0seg + c * LL) * DD + d;
        unsigned vb4  = (unsigned)base * 4u;                      // delta/u row0 byte off
        unsigned vnb4 = (unsigned)base * 64u + (unsigned)n0 * 4u; // bmat/cmat row0 byte off

        // ---- issue the whole chunk's loads back-to-back ----
        float dl[LL], uu[LL];
        f32x2 bv[LL], cv[LL];
        #pragma unroll
        for (int t = 0; t < LL; ++t) {
            unsigned oA = vb4 + (unsigned)(t * 4096);             // t*DD*4
            unsigned oB = vnb4 + (unsigned)(t * 65536);           // t*DD*NN*4
            GLD2(bv[t], oB, bmat);
            GLD2(cv[t], oB, cmat);
            GLD1(dl[t], oA, delta);
            GLD1(uu[t], oA, u);
        }
        asm volatile("s_waitcnt vmcnt(0)" ::: "memory");
        __builtin_amdgcn_sched_barrier(0);

        // ---- forward pass: cumprod / cumsum (reference order) ----
        float cpA[LL], cpB[LL], pfA[LL], pfB[LL];
        float pr0 = 1.0f, pr1 = 1.0f, s0 = 0.0f, s1 = 0.0f;
        #pragma unroll
        for (int t = 0; t < LL; ++t) {
            float dA0 = fminf(fmaxf(dl[t] * A0, -10.0f), 10.0f);
            float dA1 = fminf(fmaxf(dl[t] * A1, -10.0f), 10.0f);
            float e0 = __expf(dA0), e1 = __expf(dA1);
            float f0 = (fabsf(dA0) < 1e-4f) ? dl[t] : (e0 - 1.0f) * r0;
            float f1 = (fabsf(dA1) < 1e-4f) ? dl[t] : (e1 - 1.0f) * r1;
            pr0 *= e0; pr1 *= e1;
            cpA[t] = pr0; cpB[t] = pr1;
            float fw0 = (t < LL - 1) ? e0 : 1.0f;
            float fw1 = (t < LL - 1) ? e1 : 1.0f;
            s0 += f0 * (bv[t].x * uu[t]) * fw0;
            s1 += f1 * (bv[t].y * uu[t]) * fw1;
            pfA[t] = s0; pfB[t] = s1;
        }

        // ---- output pass ----
        #pragma unroll
        for (int t = 0; t < LL; ++t) {
            float v = cv[t].x * (h0 * cpA[t] + pfA[LL - 1 - t])
                    + cv[t].y * (h1 * cpB[t] + pfB[LL - 1 - t]);
            v += __shfl_xor(v, 1);
            v += __shfl_xor(v, 2);
            v += __shfl_xor(v, 4);              // full sum over 16 n (8 lanes x 2)
            if (ng == 0) out[base + t * DD] = v;
        }

        h0 = h0 * pr0 + pfA[0];                 // h*cp[15] + g[0]
        h1 = h1 * pr1 + pfB[0];
    }
}

// ---------------------------------------------------------------------------
extern "C" void kernel_launch(void* const* d_in, const int* in_sizes, int n_in,
                              void* d_out, int out_size, void* d_ws, size_t ws_size,
                              hipStream_t stream) {
    (void)in_sizes; (void)n_in; (void)out_size; (void)ws_size;

    const float* u     = (const float*)d_in[0];
    const float* delta = (const float*)d_in[1];
    const float* bmat  = (const float*)d_in[2];
    const float* cmat  = (const float*)d_in[3];
    const float* A_log = (const float*)d_in[4];
    float* out = (float*)d_out;

    size_t tbl = (size_t)BB * SS * DD * NN;     // 1M floats = 4 MB each
    float* Pseg = (float*)d_ws;
    float* Qseg = Pseg + tbl;
    float* hin  = Qseg + tbl;                   // 12 MB total workspace

    k1a_segxform<<<(BB * SS * DD * (NN / 2)) / 256, 256, 0, stream>>>(
        delta, u, bmat, A_log, Pseg, Qseg);
    k1b_scan<<<(BB * DD * NN) / 256, 256, 0, stream>>>(Pseg, Qseg, hin, SS);
    k2_main<<<(BB * SS * DD * (NN / 2)) / 256, 256, 0, stream>>>(
        delta, u, bmat, cmat, A_log, hin, out);
}